// Round 4
// baseline (4178.610 us; speedup 1.0000x reference)
//
#include <hip/hip_runtime.h>
#include <hip/hip_bf16.h>

// OrthogonalWight: W = Qu @ Qv, Q = product of 4096 Householder reflections.
// Compact-WY: Q = I - Vn T Vn^T,  T = R^{-1}, R = 0.5 I + triu(Vn^T Vn, 1).
// All big products as bf16 2-term-split MFMA GEMMs (hh + hl + lh), fp32 accum.
//
// Workspace layout (218 MB; guarded against ws_size):
//   slots A (2x32MB): AT splits -> memset -> Tt splits -> Vn splits (recomputed)
//   slots B (2x32MB): memset -> T splits -> (phase 2) Qv^T splits
//   slots C (2x32MB): Qu splits (persist through phase 2)
//   G (2x8MB), rnorm (16KB).  S and Xt splits live in d_out (exactly 64MB).

#define N4K 4096
#define ELN ((long)N4K * (long)N4K)

typedef __bf16 bf16x8 __attribute__((ext_vector_type(8)));
typedef float f32x4 __attribute__((ext_vector_type(4)));

__device__ __forceinline__ unsigned short f2bf(float x) {
    unsigned int u = __builtin_bit_cast(unsigned int, x);
    u += 0x7FFFu + ((u >> 16) & 1u);
    return (unsigned short)(u >> 16);
}
__device__ __forceinline__ float bf2f(unsigned short h) {
    unsigned int u = ((unsigned int)h) << 16;
    return __builtin_bit_cast(float, u);
}
__device__ __forceinline__ void split_store(float v, unsigned short* H, unsigned short* L, long idx) {
    unsigned short h = f2bf(v);
    H[idx] = h;
    L[idx] = f2bf(v - bf2f(h));
}

// ---------------- column norms ----------------
__global__ __launch_bounds__(256) void colnorm2_k(const float* __restrict__ A, float* __restrict__ out) {
    int col = blockIdx.x * 256 + threadIdx.x;
    long r0 = (long)blockIdx.y * 128;
    float s = 0.f;
    for (int r = 0; r < 128; ++r) {
        float v = A[(r0 + r) * N4K + col];
        s += v * v;
    }
    atomicAdd(&out[col], s);
}

__global__ __launch_bounds__(256) void rsqrt_k(float* x) {
    int i = blockIdx.x * 256 + threadIdx.x;
    x[i] = 1.0f / sqrtf(x[i]);
}

// ---------------- normalize + split (row-major) ----------------
__global__ __launch_bounds__(256) void normalize_split_k(const float* __restrict__ A, const float* __restrict__ rn,
                                                         unsigned short* __restrict__ H, unsigned short* __restrict__ L) {
    long i = ((long)blockIdx.x * 256 + threadIdx.x) * 4;
    float4 v = *(const float4*)(A + i);
    float4 rv = *(const float4*)(rn + (int)(i & (N4K - 1)));
    float a0 = v.x * rv.x, a1 = v.y * rv.y, a2 = v.z * rv.z, a3 = v.w * rv.w;
    ushort4 h, lo;
    h.x = f2bf(a0); lo.x = f2bf(a0 - bf2f(h.x));
    h.y = f2bf(a1); lo.y = f2bf(a1 - bf2f(h.y));
    h.z = f2bf(a2); lo.z = f2bf(a2 - bf2f(h.z));
    h.w = f2bf(a3); lo.w = f2bf(a3 - bf2f(h.w));
    *(ushort4*)(H + i) = h;
    *(ushort4*)(L + i) = lo;
}

// ---------------- transpose + normalize + split ----------------
__global__ __launch_bounds__(256) void transpose_split_k(const float* __restrict__ A, const float* __restrict__ rn,
                                                         unsigned short* __restrict__ H, unsigned short* __restrict__ L) {
    __shared__ float tile[64][65];
    int bj = blockIdx.x, bi = blockIdx.y;
    int t = threadIdx.x;
    int c = t & 63, r0 = t >> 6;
    for (int q = 0; q < 16; ++q) {
        int r = q * 4 + r0;
        tile[r][c] = A[(long)(bi * 64 + r) * N4K + bj * 64 + c];
    }
    __syncthreads();
    for (int q = 0; q < 16; ++q) {
        int orow = q * 4 + r0;
        int j = bj * 64 + orow;                 // output row = source column
        float v = tile[c][orow] * rn[j];
        long idx = (long)j * N4K + bi * 64 + c;
        unsigned short h = f2bf(v);
        H[idx] = h;
        L[idx] = f2bf(v - bf2f(h));
    }
}

// ---------------- base triangular inverse (64x64 diag blocks) ----------------
__global__ __launch_bounds__(64) void tri_inv_base64_k(const unsigned short* __restrict__ Sh, const unsigned short* __restrict__ Sl,
                                                       unsigned short* __restrict__ Th, unsigned short* __restrict__ Tl,
                                                       unsigned short* __restrict__ Tth, unsigned short* __restrict__ Ttl) {
    __shared__ float R[64][65];
    __shared__ float X[64][65];   // X[col][row]
    int b0 = blockIdx.x * 64;
    int t = threadIdx.x;          // column
    for (int r = 0; r < 64; ++r) {
        long idx = (long)(b0 + r) * N4K + b0 + t;
        float v = bf2f(Sh[idx]) + bf2f(Sl[idx]);
        R[r][t] = (t > r) ? v : 0.f;
    }
    __syncthreads();
    X[t][t] = 2.f;                // 1 / 0.5
    for (int i = t - 1; i >= 0; --i) {
        float s = 0.f;
        for (int k = i + 1; k <= t; ++k) s += R[i][k] * X[t][k];
        X[t][i] = -2.f * s;
    }
    __syncthreads();
    for (int r = 0; r < 64; ++r) {
        long idx = (long)(b0 + r) * N4K + b0 + t;
        float v = (t >= r) ? X[t][r] : 0.f;   // T[r][t]
        split_store(v, Th, Tl, idx);
        float vt = (r >= t) ? X[r][t] : 0.f;  // Tt[r][t] = T[t][r]
        split_store(vt, Tth, Ttl, idx);
    }
}

// ---------------- combine 64 -> 128 : T12 = -T11 * S12 * T22 ----------------
__global__ __launch_bounds__(256) void combine64_k(const unsigned short* __restrict__ Sh, const unsigned short* __restrict__ Sl,
                                                   unsigned short* __restrict__ Th, unsigned short* __restrict__ Tl,
                                                   unsigned short* __restrict__ Tth, unsigned short* __restrict__ Ttl) {
    __shared__ float T11[64][65], T22[64][65], P[64][65];
    int p = blockIdx.x;
    int base = 128 * p;
    int t = threadIdx.x;
    for (int q = 0; q < 16; ++q) {
        int e = q * 256 + t;
        int r = e >> 6, c = e & 63;
        long i1 = (long)(base + r) * N4K + base + c;
        T11[r][c] = bf2f(Th[i1]) + bf2f(Tl[i1]);
        long i2 = (long)(base + 64 + r) * N4K + base + 64 + c;
        T22[r][c] = bf2f(Th[i2]) + bf2f(Tl[i2]);
    }
    __syncthreads();
    int j = t & 63, i0 = t >> 6;
    for (int i = i0; i < 64; i += 4) {
        float s = 0.f;
        for (int k = 0; k < 64; ++k) {
            long is = (long)(base + i) * N4K + base + 64 + k;
            float s12 = bf2f(Sh[is]) + bf2f(Sl[is]);
            s += s12 * T22[k][j];
        }
        P[i][j] = s;
    }
    __syncthreads();
    for (int i = i0; i < 64; i += 4) {
        float s = 0.f;
        for (int k = 0; k < 64; ++k) s += T11[i][k] * P[k][j];
        float v = -s;
        long it = (long)(base + i) * N4K + base + 64 + j;
        split_store(v, Th, Tl, it);
        long itt = (long)(base + 64 + j) * N4K + base + i;
        split_store(v, Tth, Ttl, itt);
    }
}

// ---------------- split BT GEMM: C = alpha * (Ah+Al)(Bh+Bl)^T (+I), batched ----------------
__global__ __launch_bounds__(256) void gemm_split_bt(
    const unsigned short* __restrict__ Ah, const unsigned short* __restrict__ Al, long lda, long sA,
    const unsigned short* __restrict__ Bh, const unsigned short* __restrict__ Bl, long ldb, long sB,
    float* __restrict__ Cf, unsigned short* __restrict__ Ch, unsigned short* __restrict__ Cl, long ldc, long sC,
    int K, float alpha, int addI) {
    __shared__ unsigned short sAh[128 * 32], sAl[128 * 32], sBh[128 * 32], sBl[128 * 32];
    int tid = threadIdx.x;
    int bx = blockIdx.x, by = blockIdx.y, bz = blockIdx.z;
    const unsigned short* pAh = Ah + (long)bz * sA + (long)by * 128 * lda;
    const unsigned short* pAl = Al + (long)bz * sA + (long)by * 128 * lda;
    const unsigned short* pBh = Bh + (long)bz * sB + (long)bx * 128 * ldb;
    const unsigned short* pBl = Bl + (long)bz * sB + (long)bx * 128 * ldb;
    int ilda = (int)lda, ildb = (int)ldb;

    int ch0 = tid, ch1 = tid + 256;
    int r0 = ch0 >> 2, c0 = ch0 & 3;
    int r1 = ch1 >> 2, c1 = ch1 & 3;
    int gA0 = r0 * ilda + c0 * 8, gA1 = r1 * ilda + c1 * 8;
    int gB0 = r0 * ildb + c0 * 8, gB1 = r1 * ildb + c1 * 8;
    int l0 = r0 * 32 + ((c0 ^ ((r0 >> 1) & 3)) << 3);
    int l1 = r1 * 32 + ((c1 ^ ((r1 >> 1) & 3)) << 3);

    int w = tid >> 6, l = tid & 63;
    int wm = w >> 1, wn = w & 1;
    int aoff[4], boff[4];
#pragma unroll
    for (int m = 0; m < 4; ++m) {
        int rowa = wm * 64 + m * 16 + (l & 15);
        aoff[m] = rowa * 32 + (((l >> 4) ^ ((rowa >> 1) & 3)) << 3);
        int rowb = wn * 64 + m * 16 + (l & 15);
        boff[m] = rowb * 32 + (((l >> 4) ^ ((rowb >> 1) & 3)) << 3);
    }

    f32x4 acc[4][4];
#pragma unroll
    for (int m = 0; m < 4; ++m)
#pragma unroll
        for (int n = 0; n < 4; ++n) acc[m][n] = (f32x4){0.f, 0.f, 0.f, 0.f};

    uint4 ra0 = *(const uint4*)(pAh + gA0), ra1 = *(const uint4*)(pAh + gA1);
    uint4 rb0 = *(const uint4*)(pAl + gA0), rb1 = *(const uint4*)(pAl + gA1);
    uint4 rc0 = *(const uint4*)(pBh + gB0), rc1 = *(const uint4*)(pBh + gB1);
    uint4 rd0 = *(const uint4*)(pBl + gB0), rd1 = *(const uint4*)(pBl + gB1);

    int nk = K >> 5;
#pragma unroll 1
    for (int kt = 0; kt < nk; ++kt) {
        __syncthreads();
        *(uint4*)&sAh[l0] = ra0; *(uint4*)&sAh[l1] = ra1;
        *(uint4*)&sAl[l0] = rb0; *(uint4*)&sAl[l1] = rb1;
        *(uint4*)&sBh[l0] = rc0; *(uint4*)&sBh[l1] = rc1;
        *(uint4*)&sBl[l0] = rd0; *(uint4*)&sBl[l1] = rd1;
        __syncthreads();
        if (kt + 1 < nk) {  // prefetch next K-slab early; latency hides under MFMA
            pAh += 32; pAl += 32; pBh += 32; pBl += 32;
            ra0 = *(const uint4*)(pAh + gA0); ra1 = *(const uint4*)(pAh + gA1);
            rb0 = *(const uint4*)(pAl + gA0); rb1 = *(const uint4*)(pAl + gA1);
            rc0 = *(const uint4*)(pBh + gB0); rc1 = *(const uint4*)(pBh + gB1);
            rd0 = *(const uint4*)(pBl + gB0); rd1 = *(const uint4*)(pBl + gB1);
        }
        bf16x8 fah[4], fal[4], fbh[4], fbl[4];
#pragma unroll
        for (int m = 0; m < 4; ++m) {
            fah[m] = *(const bf16x8*)&sAh[aoff[m]];
            fal[m] = *(const bf16x8*)&sAl[aoff[m]];
            fbh[m] = *(const bf16x8*)&sBh[boff[m]];
            fbl[m] = *(const bf16x8*)&sBl[boff[m]];
        }
#pragma unroll
        for (int m = 0; m < 4; ++m)
#pragma unroll
            for (int n = 0; n < 4; ++n) {
                acc[m][n] = __builtin_amdgcn_mfma_f32_16x16x32_bf16(fah[m], fbh[n], acc[m][n], 0, 0, 0);
                acc[m][n] = __builtin_amdgcn_mfma_f32_16x16x32_bf16(fah[m], fbl[n], acc[m][n], 0, 0, 0);
                acc[m][n] = __builtin_amdgcn_mfma_f32_16x16x32_bf16(fal[m], fbh[n], acc[m][n], 0, 0, 0);
            }
    }

    float* CfZ = Cf ? (Cf + (long)bz * sC) : nullptr;
    unsigned short* ChZ = Ch ? (Ch + (long)bz * sC) : nullptr;
    unsigned short* ClZ = Cl ? (Cl + (long)bz * sC) : nullptr;
    int r16 = (l >> 4) * 4, c16 = l & 15;
#pragma unroll
    for (int m = 0; m < 4; ++m)
#pragma unroll
        for (int n = 0; n < 4; ++n)
#pragma unroll
            for (int r = 0; r < 4; ++r) {
                int row = by * 128 + wm * 64 + m * 16 + r16 + r;
                int col = bx * 128 + wn * 64 + n * 16 + c16;
                float v = acc[m][n][r] * alpha;
                if (addI && row == col) v += 1.0f;
                long idx = (long)row * ldc + col;
                if (CfZ) CfZ[idx] = v;
                if (ChZ) {
                    unsigned short h = f2bf(v);
                    ChZ[idx] = h;
                    ClZ[idx] = f2bf(v - bf2f(h));
                }
            }
}

// ---------------- host side ----------------
struct Bufs {
    // slot pair A: AT -> Tt -> Vn ; slot pair B: T -> (phase2) Qv^T ; slot pair C: Qu
    unsigned short *Ah, *Al, *Th, *Tl, *Quh, *Qul, *Gh, *Gl;
    unsigned short *Sh, *Sl;  // d_out (also reused as Xt)
    float* rnorm;
};

static inline void launch_gemm(const unsigned short* Ah, const unsigned short* Al, long lda, long sA,
                               const unsigned short* Bh, const unsigned short* Bl, long ldb, long sB,
                               float* Cf, unsigned short* Ch, unsigned short* Cl, long ldc, long sC,
                               int M, int Nn, int K, float alpha, int addI, int Z, hipStream_t stream) {
    dim3 grid(Nn / 128, M / 128, Z);
    gemm_split_bt<<<grid, dim3(256), 0, stream>>>(Ah, Al, lda, sA, Bh, Bl, ldb, sB, Cf, Ch, Cl, ldc, sC, K, alpha, addI);
}

static void run_phase(const float* inp, const Bufs& B, bool left, hipStream_t s) {
    const size_t sz = (size_t)ELN * 2;
    unsigned short* Tth = B.Ah;  // Tt shares slot pair A (AT dead after S GEMM)
    unsigned short* Ttl = B.Al;
    hipMemsetAsync(B.rnorm, 0, N4K * sizeof(float), s);
    colnorm2_k<<<dim3(16, 32), dim3(256), 0, s>>>(inp, B.rnorm);
    rsqrt_k<<<dim3(16), dim3(256), 0, s>>>(B.rnorm);
    // AT = Vn^T -> slots A
    transpose_split_k<<<dim3(64, 64), dim3(256), 0, s>>>(inp, B.rnorm, B.Ah, B.Al);
    // S = Vn^T Vn = AT * AT^T -> d_out
    launch_gemm(B.Ah, B.Al, N4K, 0, B.Ah, B.Al, N4K, 0, nullptr, B.Sh, B.Sl, N4K, 0,
                N4K, N4K, N4K, 1.f, 0, 1, s);
    // zero T (slots B, first use this phase) and Tt (slots A, AT now dead):
    // block-lower regions must read as 0 in dense-blind GEMMs
    hipMemsetAsync(B.Th, 0, sz, s);
    hipMemsetAsync(B.Tl, 0, sz, s);
    hipMemsetAsync(Tth, 0, sz, s);
    hipMemsetAsync(Ttl, 0, sz, s);
    // T = R^{-1}: base 64 blocks, combine to 128, then doubling 128..2048
    tri_inv_base64_k<<<dim3(64), dim3(64), 0, s>>>(B.Sh, B.Sl, B.Th, B.Tl, Tth, Ttl);
    combine64_k<<<dim3(32), dim3(256), 0, s>>>(B.Sh, B.Sl, B.Th, B.Tl, Tth, Ttl);
    for (int m = 128; m <= 2048; m <<= 1) {
        int Z = N4K / (2 * m);
        long sdiag = (long)2 * m * (N4K + 1);
        long offT22 = (long)m * (N4K + 1);
        // G = T11 * S12 = T11 * S21^T   (S symmetric, fully materialized)
        launch_gemm(B.Th, B.Tl, N4K, sdiag, B.Sh + (long)m * N4K, B.Sl + (long)m * N4K, N4K, sdiag,
                    nullptr, B.Gh, B.Gl, m, (long)m * m, m, m, m, 1.f, 0, Z, s);
        // T12 = -G * T22 = -G * (T22t)^T
        launch_gemm(B.Gh, B.Gl, m, (long)m * m, Tth + offT22, Ttl + offT22, N4K, sdiag,
                    nullptr, B.Th + m, B.Tl + m, N4K, sdiag, m, m, m, -1.f, 0, Z, s);
        // T12t = -T22t * G^T
        launch_gemm(Tth + offT22, Ttl + offT22, N4K, sdiag, B.Gh, B.Gl, m, (long)m * m,
                    nullptr, Tth + (long)m * N4K, Ttl + (long)m * N4K, N4K, sdiag, m, m, m, -1.f, 0, Z, s);
    }
    // Vn -> slots A (Tt dead after doubling); fully overwritten, no memset needed
    normalize_split_k<<<dim3(16384), dim3(256), 0, s>>>(inp, B.rnorm, B.Ah, B.Al);
    // Xt = Vn * T^T -> d_out (S dead; GEMM reads only Vn and T)
    launch_gemm(B.Ah, B.Al, N4K, 0, B.Th, B.Tl, N4K, 0, nullptr, B.Sh, B.Sl, N4K, 0,
                N4K, N4K, N4K, 1.f, 0, 1, s);
    if (left) {
        // Qu = I - Vn * Xt^T -> slots C
        launch_gemm(B.Ah, B.Al, N4K, 0, B.Sh, B.Sl, N4K, 0, nullptr, B.Quh, B.Qul, N4K, 0,
                    N4K, N4K, N4K, -1.f, 1, 1, s);
    } else {
        // Qv^T = I - Xt_v * Vn^T -> slots B (T dead after Xt GEMM)
        launch_gemm(B.Sh, B.Sl, N4K, 0, B.Ah, B.Al, N4K, 0, nullptr, B.Th, B.Tl, N4K, 0,
                    N4K, N4K, N4K, -1.f, 1, 1, s);
    }
}

extern "C" void kernel_launch(void* const* d_in, const int* in_sizes, int n_in,
                              void* d_out, int out_size, void* d_ws, size_t ws_size,
                              hipStream_t stream) {
    const float* U = (const float*)d_in[0];
    const float* V = (const float*)d_in[1];
    const size_t sz = (size_t)ELN * 2;            // one bf16 matrix (32 MB)
    const size_t gsz = (size_t)2048 * 2048 * 2;   // G half (8 MB)
    const size_t need = 6 * sz + 2 * gsz + (size_t)N4K * sizeof(float);
    if (ws_size < need) {
        // diagnosable fallback: clean absmax failure instead of an OOB crash
        hipMemsetAsync(d_out, 0, (size_t)out_size * sizeof(float), stream);
        return;
    }
    char* w = (char*)d_ws;
    Bufs B;
    B.Ah = (unsigned short*)w; w += sz;   // slot pair A
    B.Al = (unsigned short*)w; w += sz;
    B.Th = (unsigned short*)w; w += sz;   // slot pair B
    B.Tl = (unsigned short*)w; w += sz;
    B.Quh = (unsigned short*)w; w += sz;  // slot pair C
    B.Qul = (unsigned short*)w; w += sz;
    B.Gh = (unsigned short*)w; w += gsz;
    B.Gl = (unsigned short*)w; w += gsz;
    B.rnorm = (float*)w; w += (size_t)N4K * sizeof(float);
    // S / Xt splits live in d_out (exactly out bytes = 64 MB)
    B.Sh = (unsigned short*)d_out;
    B.Sl = B.Sh + ELN;

    run_phase(U, B, true, stream);   // Qu -> slots C
    run_phase(V, B, false, stream);  // Qv^T -> slots B
    // W = Qu * Qv = Qu * (Qv^T)^T  -> f32 straight to d_out (Xt dead)
    launch_gemm(B.Quh, B.Qul, N4K, 0, B.Th, B.Tl, N4K, 0, (float*)d_out, nullptr, nullptr, N4K, 0,
                N4K, N4K, N4K, 1.f, 0, 1, stream);
}

// Round 5
// 3913.788 us; speedup vs baseline: 1.0677x; 1.0677x over previous
//
#include <hip/hip_runtime.h>
#include <hip/hip_bf16.h>

// OrthogonalWight: W = Qu @ Qv, Q = product of 4096 Householder reflections.
// Compact-WY: Q = I - Vn T Vn^T,  T = R^{-1}, R = 0.5 I + triu(Vn^T Vn, 1).
// All big products as bf16 2-term-split MFMA GEMMs (hh + hl + lh), fp32 accum.
// R5: exploit structure — S symmetric (mirror-write upper->lower),
//     T upper-triangular (K-loop start/end clipping in Xt and doubling GEMMs).

#define N4K 4096
#define ELN ((long)N4K * (long)N4K)

typedef __bf16 bf16x8 __attribute__((ext_vector_type(8)));
typedef float f32x4 __attribute__((ext_vector_type(4)));

__device__ __forceinline__ unsigned short f2bf(float x) {
    unsigned int u = __builtin_bit_cast(unsigned int, x);
    u += 0x7FFFu + ((u >> 16) & 1u);
    return (unsigned short)(u >> 16);
}
__device__ __forceinline__ float bf2f(unsigned short h) {
    unsigned int u = ((unsigned int)h) << 16;
    return __builtin_bit_cast(float, u);
}
__device__ __forceinline__ void split_store(float v, unsigned short* H, unsigned short* L, long idx) {
    unsigned short h = f2bf(v);
    H[idx] = h;
    L[idx] = f2bf(v - bf2f(h));
}

// ---------------- column norms ----------------
__global__ __launch_bounds__(256) void colnorm2_k(const float* __restrict__ A, float* __restrict__ out) {
    int col = blockIdx.x * 256 + threadIdx.x;
    long r0 = (long)blockIdx.y * 128;
    float s = 0.f;
    for (int r = 0; r < 128; ++r) {
        float v = A[(r0 + r) * N4K + col];
        s += v * v;
    }
    atomicAdd(&out[col], s);
}

__global__ __launch_bounds__(256) void rsqrt_k(float* x) {
    int i = blockIdx.x * 256 + threadIdx.x;
    x[i] = 1.0f / sqrtf(x[i]);
}

// ---------------- normalize + split (row-major) ----------------
__global__ __launch_bounds__(256) void normalize_split_k(const float* __restrict__ A, const float* __restrict__ rn,
                                                         unsigned short* __restrict__ H, unsigned short* __restrict__ L) {
    long i = ((long)blockIdx.x * 256 + threadIdx.x) * 4;
    float4 v = *(const float4*)(A + i);
    float4 rv = *(const float4*)(rn + (int)(i & (N4K - 1)));
    float a0 = v.x * rv.x, a1 = v.y * rv.y, a2 = v.z * rv.z, a3 = v.w * rv.w;
    ushort4 h, lo;
    h.x = f2bf(a0); lo.x = f2bf(a0 - bf2f(h.x));
    h.y = f2bf(a1); lo.y = f2bf(a1 - bf2f(h.y));
    h.z = f2bf(a2); lo.z = f2bf(a2 - bf2f(h.z));
    h.w = f2bf(a3); lo.w = f2bf(a3 - bf2f(h.w));
    *(ushort4*)(H + i) = h;
    *(ushort4*)(L + i) = lo;
}

// ---------------- transpose + normalize + split ----------------
__global__ __launch_bounds__(256) void transpose_split_k(const float* __restrict__ A, const float* __restrict__ rn,
                                                         unsigned short* __restrict__ H, unsigned short* __restrict__ L) {
    __shared__ float tile[64][65];
    int bj = blockIdx.x, bi = blockIdx.y;
    int t = threadIdx.x;
    int c = t & 63, r0 = t >> 6;
    for (int q = 0; q < 16; ++q) {
        int r = q * 4 + r0;
        tile[r][c] = A[(long)(bi * 64 + r) * N4K + bj * 64 + c];
    }
    __syncthreads();
    for (int q = 0; q < 16; ++q) {
        int orow = q * 4 + r0;
        int j = bj * 64 + orow;                 // output row = source column
        float v = tile[c][orow] * rn[j];
        long idx = (long)j * N4K + bi * 64 + c;
        unsigned short h = f2bf(v);
        H[idx] = h;
        L[idx] = f2bf(v - bf2f(h));
    }
}

// ---------------- base triangular inverse (64x64 diag blocks) ----------------
__global__ __launch_bounds__(64) void tri_inv_base64_k(const unsigned short* __restrict__ Sh, const unsigned short* __restrict__ Sl,
                                                       unsigned short* __restrict__ Th, unsigned short* __restrict__ Tl,
                                                       unsigned short* __restrict__ Tth, unsigned short* __restrict__ Ttl) {
    __shared__ float R[64][65];
    __shared__ float X[64][65];   // X[col][row]
    int b0 = blockIdx.x * 64;
    int t = threadIdx.x;          // column
    for (int r = 0; r < 64; ++r) {
        long idx = (long)(b0 + r) * N4K + b0 + t;
        float v = bf2f(Sh[idx]) + bf2f(Sl[idx]);
        R[r][t] = (t > r) ? v : 0.f;
    }
    __syncthreads();
    X[t][t] = 2.f;                // 1 / 0.5
    for (int i = t - 1; i >= 0; --i) {
        float s = 0.f;
        for (int k = i + 1; k <= t; ++k) s += R[i][k] * X[t][k];
        X[t][i] = -2.f * s;
    }
    __syncthreads();
    for (int r = 0; r < 64; ++r) {
        long idx = (long)(b0 + r) * N4K + b0 + t;
        float v = (t >= r) ? X[t][r] : 0.f;   // T[r][t]
        split_store(v, Th, Tl, idx);
        float vt = (r >= t) ? X[r][t] : 0.f;  // Tt[r][t] = T[t][r]
        split_store(vt, Tth, Ttl, idx);
    }
}

// ---------------- combine 64 -> 128 : T12 = -T11 * S12 * T22 ----------------
__global__ __launch_bounds__(256) void combine64_k(const unsigned short* __restrict__ Sh, const unsigned short* __restrict__ Sl,
                                                   unsigned short* __restrict__ Th, unsigned short* __restrict__ Tl,
                                                   unsigned short* __restrict__ Tth, unsigned short* __restrict__ Ttl) {
    __shared__ float T11[64][65], T22[64][65], P[64][65];
    int p = blockIdx.x;
    int base = 128 * p;
    int t = threadIdx.x;
    for (int q = 0; q < 16; ++q) {
        int e = q * 256 + t;
        int r = e >> 6, c = e & 63;
        long i1 = (long)(base + r) * N4K + base + c;
        T11[r][c] = bf2f(Th[i1]) + bf2f(Tl[i1]);
        long i2 = (long)(base + 64 + r) * N4K + base + 64 + c;
        T22[r][c] = bf2f(Th[i2]) + bf2f(Tl[i2]);
    }
    __syncthreads();
    int j = t & 63, i0 = t >> 6;
    for (int i = i0; i < 64; i += 4) {
        float s = 0.f;
        for (int k = 0; k < 64; ++k) {
            long is = (long)(base + i) * N4K + base + 64 + k;
            float s12 = bf2f(Sh[is]) + bf2f(Sl[is]);
            s += s12 * T22[k][j];
        }
        P[i][j] = s;
    }
    __syncthreads();
    for (int i = i0; i < 64; i += 4) {
        float s = 0.f;
        for (int k = 0; k < 64; ++k) s += T11[i][k] * P[k][j];
        float v = -s;
        long it = (long)(base + i) * N4K + base + 64 + j;
        split_store(v, Th, Tl, it);
        long itt = (long)(base + 64 + j) * N4K + base + i;
        split_store(v, Tth, Ttl, itt);
    }
}

// ---------------- split BT GEMM: C = alpha * (Ah+Al)(Bh+Bl)^T (+I), batched ----------------
// K-loop clipping: kt0 = kt0m_by*by + kt0m_bx*bx; kte = min over enabled
// ktem_*(idx+1). symm: skip bx<by blocks, mirror-write transposed block.
__global__ __launch_bounds__(256) void gemm_split_bt(
    const unsigned short* __restrict__ Ah, const unsigned short* __restrict__ Al, long lda, long sA,
    const unsigned short* __restrict__ Bh, const unsigned short* __restrict__ Bl, long ldb, long sB,
    float* __restrict__ Cf, unsigned short* __restrict__ Ch, unsigned short* __restrict__ Cl, long ldc, long sC,
    int K, float alpha, int addI,
    int kt0m_by, int kt0m_bx, int ktem_by, int ktem_bx, int symm) {
    __shared__ unsigned short sAh[128 * 32], sAl[128 * 32], sBh[128 * 32], sBl[128 * 32];
    int tid = threadIdx.x;
    int bx = blockIdx.x, by = blockIdx.y, bz = blockIdx.z;
    if (symm && bx < by) return;  // uniform per-block: safe before barriers
    int nk = K >> 5;
    int kt0 = kt0m_by * by + kt0m_bx * bx;
    int kte = nk;
    if (ktem_by) { int e = ktem_by * (by + 1); kte = e < kte ? e : kte; }
    if (ktem_bx) { int e = ktem_bx * (bx + 1); kte = e < kte ? e : kte; }

    const unsigned short* pAh = Ah + (long)bz * sA + (long)by * 128 * lda + (long)kt0 * 32;
    const unsigned short* pAl = Al + (long)bz * sA + (long)by * 128 * lda + (long)kt0 * 32;
    const unsigned short* pBh = Bh + (long)bz * sB + (long)bx * 128 * ldb + (long)kt0 * 32;
    const unsigned short* pBl = Bl + (long)bz * sB + (long)bx * 128 * ldb + (long)kt0 * 32;
    int ilda = (int)lda, ildb = (int)ldb;

    int ch0 = tid, ch1 = tid + 256;
    int r0 = ch0 >> 2, c0 = ch0 & 3;
    int r1 = ch1 >> 2, c1 = ch1 & 3;
    int gA0 = r0 * ilda + c0 * 8, gA1 = r1 * ilda + c1 * 8;
    int gB0 = r0 * ildb + c0 * 8, gB1 = r1 * ildb + c1 * 8;
    int l0 = r0 * 32 + ((c0 ^ ((r0 >> 1) & 3)) << 3);
    int l1 = r1 * 32 + ((c1 ^ ((r1 >> 1) & 3)) << 3);

    int w = tid >> 6, l = tid & 63;
    int wm = w >> 1, wn = w & 1;
    int aoff[4], boff[4];
#pragma unroll
    for (int m = 0; m < 4; ++m) {
        int rowa = wm * 64 + m * 16 + (l & 15);
        aoff[m] = rowa * 32 + (((l >> 4) ^ ((rowa >> 1) & 3)) << 3);
        int rowb = wn * 64 + m * 16 + (l & 15);
        boff[m] = rowb * 32 + (((l >> 4) ^ ((rowb >> 1) & 3)) << 3);
    }

    f32x4 acc[4][4];
#pragma unroll
    for (int m = 0; m < 4; ++m)
#pragma unroll
        for (int n = 0; n < 4; ++n) acc[m][n] = (f32x4){0.f, 0.f, 0.f, 0.f};

    uint4 ra0 = *(const uint4*)(pAh + gA0), ra1 = *(const uint4*)(pAh + gA1);
    uint4 rb0 = *(const uint4*)(pAl + gA0), rb1 = *(const uint4*)(pAl + gA1);
    uint4 rc0 = *(const uint4*)(pBh + gB0), rc1 = *(const uint4*)(pBh + gB1);
    uint4 rd0 = *(const uint4*)(pBl + gB0), rd1 = *(const uint4*)(pBl + gB1);

#pragma unroll 1
    for (int kt = kt0; kt < kte; ++kt) {
        __syncthreads();
        *(uint4*)&sAh[l0] = ra0; *(uint4*)&sAh[l1] = ra1;
        *(uint4*)&sAl[l0] = rb0; *(uint4*)&sAl[l1] = rb1;
        *(uint4*)&sBh[l0] = rc0; *(uint4*)&sBh[l1] = rc1;
        *(uint4*)&sBl[l0] = rd0; *(uint4*)&sBl[l1] = rd1;
        __syncthreads();
        if (kt + 1 < kte) {  // prefetch next K-slab early; latency hides under MFMA
            pAh += 32; pAl += 32; pBh += 32; pBl += 32;
            ra0 = *(const uint4*)(pAh + gA0); ra1 = *(const uint4*)(pAh + gA1);
            rb0 = *(const uint4*)(pAl + gA0); rb1 = *(const uint4*)(pAl + gA1);
            rc0 = *(const uint4*)(pBh + gB0); rc1 = *(const uint4*)(pBh + gB1);
            rd0 = *(const uint4*)(pBl + gB0); rd1 = *(const uint4*)(pBl + gB1);
        }
        bf16x8 fah[4], fal[4], fbh[4], fbl[4];
#pragma unroll
        for (int m = 0; m < 4; ++m) {
            fah[m] = *(const bf16x8*)&sAh[aoff[m]];
            fal[m] = *(const bf16x8*)&sAl[aoff[m]];
            fbh[m] = *(const bf16x8*)&sBh[boff[m]];
            fbl[m] = *(const bf16x8*)&sBl[boff[m]];
        }
#pragma unroll
        for (int m = 0; m < 4; ++m)
#pragma unroll
            for (int n = 0; n < 4; ++n) {
                acc[m][n] = __builtin_amdgcn_mfma_f32_16x16x32_bf16(fah[m], fbh[n], acc[m][n], 0, 0, 0);
                acc[m][n] = __builtin_amdgcn_mfma_f32_16x16x32_bf16(fah[m], fbl[n], acc[m][n], 0, 0, 0);
                acc[m][n] = __builtin_amdgcn_mfma_f32_16x16x32_bf16(fal[m], fbh[n], acc[m][n], 0, 0, 0);
            }
    }

    float* CfZ = Cf ? (Cf + (long)bz * sC) : nullptr;
    unsigned short* ChZ = Ch ? (Ch + (long)bz * sC) : nullptr;
    unsigned short* ClZ = Cl ? (Cl + (long)bz * sC) : nullptr;
    int r16 = (l >> 4) * 4, c16 = l & 15;
#pragma unroll
    for (int m = 0; m < 4; ++m)
#pragma unroll
        for (int n = 0; n < 4; ++n)
#pragma unroll
            for (int r = 0; r < 4; ++r) {
                int row = by * 128 + wm * 64 + m * 16 + r16 + r;
                int col = bx * 128 + wn * 64 + n * 16 + c16;
                float v = acc[m][n][r] * alpha;
                if (addI && row == col) v += 1.0f;
                long idx = (long)row * ldc + col;
                if (CfZ) CfZ[idx] = v;
                if (ChZ) {
                    unsigned short h = f2bf(v);
                    ChZ[idx] = h;
                    ClZ[idx] = f2bf(v - bf2f(h));
                }
            }
    // symmetric mirror: write transposed block to (bx,by)
    if (symm && bx > by && ChZ) {
#pragma unroll
        for (int m = 0; m < 4; ++m)
#pragma unroll
            for (int n = 0; n < 4; ++n) {
                int mrow = bx * 128 + wn * 64 + n * 16 + c16;       // mirror row = col
                int mcol = by * 128 + wm * 64 + m * 16 + r16;       // mirror col base = row
                ushort4 th, tl;
                float v0 = acc[m][n][0] * alpha, v1 = acc[m][n][1] * alpha;
                float v2 = acc[m][n][2] * alpha, v3 = acc[m][n][3] * alpha;
                th.x = f2bf(v0); tl.x = f2bf(v0 - bf2f(th.x));
                th.y = f2bf(v1); tl.y = f2bf(v1 - bf2f(th.y));
                th.z = f2bf(v2); tl.z = f2bf(v2 - bf2f(th.z));
                th.w = f2bf(v3); tl.w = f2bf(v3 - bf2f(th.w));
                long midx = (long)mrow * ldc + mcol;
                *(ushort4*)&ChZ[midx] = th;
                *(ushort4*)&ClZ[midx] = tl;
            }
    }
}

// ---------------- host side ----------------
struct Bufs {
    // slot pair A: AT -> Tt -> Vn ; slot pair B: T -> (phase2) Qv^T ; slot pair C: Qu
    unsigned short *Ah, *Al, *Th, *Tl, *Quh, *Qul, *Gh, *Gl;
    unsigned short *Sh, *Sl;  // d_out (also reused as Xt)
    float* rnorm;
};

static inline void launch_gemm(const unsigned short* Ah, const unsigned short* Al, long lda, long sA,
                               const unsigned short* Bh, const unsigned short* Bl, long ldb, long sB,
                               float* Cf, unsigned short* Ch, unsigned short* Cl, long ldc, long sC,
                               int M, int Nn, int K, float alpha, int addI, int Z, hipStream_t stream,
                               int kt0m_by = 0, int kt0m_bx = 0, int ktem_by = 0, int ktem_bx = 0, int symm = 0) {
    dim3 grid(Nn / 128, M / 128, Z);
    gemm_split_bt<<<grid, dim3(256), 0, stream>>>(Ah, Al, lda, sA, Bh, Bl, ldb, sB, Cf, Ch, Cl, ldc, sC,
                                                  K, alpha, addI, kt0m_by, kt0m_bx, ktem_by, ktem_bx, symm);
}

static void run_phase(const float* inp, const Bufs& B, bool left, hipStream_t s) {
    const size_t sz = (size_t)ELN * 2;
    unsigned short* Tth = B.Ah;  // Tt shares slot pair A (AT dead after S GEMM)
    unsigned short* Ttl = B.Al;
    hipMemsetAsync(B.rnorm, 0, N4K * sizeof(float), s);
    colnorm2_k<<<dim3(16, 32), dim3(256), 0, s>>>(inp, B.rnorm);
    rsqrt_k<<<dim3(16), dim3(256), 0, s>>>(B.rnorm);
    // AT = Vn^T -> slots A
    transpose_split_k<<<dim3(64, 64), dim3(256), 0, s>>>(inp, B.rnorm, B.Ah, B.Al);
    // S = Vn^T Vn = AT * AT^T -> d_out  (symmetric: upper blocks + mirror)
    launch_gemm(B.Ah, B.Al, N4K, 0, B.Ah, B.Al, N4K, 0, nullptr, B.Sh, B.Sl, N4K, 0,
                N4K, N4K, N4K, 1.f, 0, 1, s, 0, 0, 0, 0, /*symm=*/1);
    // zero T (slots B) and Tt (slots A, AT now dead)
    hipMemsetAsync(B.Th, 0, sz, s);
    hipMemsetAsync(B.Tl, 0, sz, s);
    hipMemsetAsync(Tth, 0, sz, s);
    hipMemsetAsync(Ttl, 0, sz, s);
    // T = R^{-1}: base 64 blocks, combine to 128, then doubling 128..2048
    tri_inv_base64_k<<<dim3(64), dim3(64), 0, s>>>(B.Sh, B.Sl, B.Th, B.Tl, Tth, Ttl);
    combine64_k<<<dim3(32), dim3(256), 0, s>>>(B.Sh, B.Sl, B.Th, B.Tl, Tth, Ttl);
    for (int m = 128; m <= 2048; m <<= 1) {
        int Z = N4K / (2 * m);
        long sdiag = (long)2 * m * (N4K + 1);
        long offT22 = (long)m * (N4K + 1);
        // G = T11 * S12 = T11 * S21^T  (T11 upper-tri: k >= row  -> kt0m_by=4)
        launch_gemm(B.Th, B.Tl, N4K, sdiag, B.Sh + (long)m * N4K, B.Sl + (long)m * N4K, N4K, sdiag,
                    nullptr, B.Gh, B.Gl, m, (long)m * m, m, m, m, 1.f, 0, Z, s, 4, 0, 0, 0, 0);
        // T12 = -G * T22 = -G * (T22t)^T  (T22t lower-tri: k <= col -> ktem_bx=4)
        launch_gemm(B.Gh, B.Gl, m, (long)m * m, Tth + offT22, Ttl + offT22, N4K, sdiag,
                    nullptr, B.Th + m, B.Tl + m, N4K, sdiag, m, m, m, -1.f, 0, Z, s, 0, 0, 0, 4, 0);
        // T12t = -T22t * G^T  (T22t rows: k <= row -> ktem_by=4)
        launch_gemm(Tth + offT22, Ttl + offT22, N4K, sdiag, B.Gh, B.Gl, m, (long)m * m,
                    nullptr, Tth + (long)m * N4K, Ttl + (long)m * N4K, N4K, sdiag, m, m, m, -1.f, 0, Z, s, 0, 0, 4, 0, 0);
    }
    // Vn -> slots A (Tt dead after doubling)
    normalize_split_k<<<dim3(16384), dim3(256), 0, s>>>(inp, B.rnorm, B.Ah, B.Al);
    // Xt = Vn * T^T -> d_out  (T rows j nonzero for k>=j -> kt0m_bx=4)
    launch_gemm(B.Ah, B.Al, N4K, 0, B.Th, B.Tl, N4K, 0, nullptr, B.Sh, B.Sl, N4K, 0,
                N4K, N4K, N4K, 1.f, 0, 1, s, 0, 4, 0, 0, 0);
    if (left) {
        // Qu = I - Vn * Xt^T -> slots C
        launch_gemm(B.Ah, B.Al, N4K, 0, B.Sh, B.Sl, N4K, 0, nullptr, B.Quh, B.Qul, N4K, 0,
                    N4K, N4K, N4K, -1.f, 1, 1, s);
    } else {
        // Qv^T = I - Xt_v * Vn^T -> slots B (T dead after Xt GEMM)
        launch_gemm(B.Sh, B.Sl, N4K, 0, B.Ah, B.Al, N4K, 0, nullptr, B.Th, B.Tl, N4K, 0,
                    N4K, N4K, N4K, -1.f, 1, 1, s);
    }
}

extern "C" void kernel_launch(void* const* d_in, const int* in_sizes, int n_in,
                              void* d_out, int out_size, void* d_ws, size_t ws_size,
                              hipStream_t stream) {
    const float* U = (const float*)d_in[0];
    const float* V = (const float*)d_in[1];
    const size_t sz = (size_t)ELN * 2;            // one bf16 matrix (32 MB)
    const size_t gsz = (size_t)2048 * 2048 * 2;   // G half (8 MB)
    const size_t need = 6 * sz + 2 * gsz + (size_t)N4K * sizeof(float);
    if (ws_size < need) {
        hipMemsetAsync(d_out, 0, (size_t)out_size * sizeof(float), stream);
        return;
    }
    char* w = (char*)d_ws;
    Bufs B;
    B.Ah = (unsigned short*)w; w += sz;   // slot pair A
    B.Al = (unsigned short*)w; w += sz;
    B.Th = (unsigned short*)w; w += sz;   // slot pair B
    B.Tl = (unsigned short*)w; w += sz;
    B.Quh = (unsigned short*)w; w += sz;  // slot pair C
    B.Qul = (unsigned short*)w; w += sz;
    B.Gh = (unsigned short*)w; w += gsz;
    B.Gl = (unsigned short*)w; w += gsz;
    B.rnorm = (float*)w; w += (size_t)N4K * sizeof(float);
    // S / Xt splits live in d_out (exactly out bytes = 64 MB)
    B.Sh = (unsigned short*)d_out;
    B.Sl = B.Sh + ELN;

    run_phase(U, B, true, stream);   // Qu -> slots C
    run_phase(V, B, false, stream);  // Qv^T -> slots B
    // W = Qu * Qv = Qu * (Qv^T)^T  -> f32 straight to d_out (Xt dead)
    launch_gemm(B.Quh, B.Qul, N4K, 0, B.Th, B.Tl, N4K, 0, (float*)d_out, nullptr, nullptr, N4K, 0,
                N4K, N4K, N4K, 1.f, 0, 1, stream);
}